// Round 6
// baseline (2672.068 us; speedup 1.0000x reference)
//
#include <hip/hip_runtime.h>
#include <stdint.h>

// Problem constants (B=4, N=16384, NP=4096) — ALL TENSORS FLOAT32.
#define QT   65536
#define NPTS 4096
#define C1   128
#define C2   256
#define CIN  384
#define COUT 128

// LDS overlay (phases strictly barrier-separated):
//  Phase A: cand float4[1024] @0 (16384 B)
//           mgK  f32[3*64*5]  @16384 (3840 B)
//           mgI  i32[3*64*5]  @20224 (3840 B)          end 24064
//  Phase B: Xs f32[64][129] @0 (33024 B); then Hh f32[64][129] @0 (33024 B)
#define SMEM_BYTES 33024

__global__ __launch_bounds__(256) void fused_fp(
    const float* __restrict__ xyz1, const float* __restrict__ xyz2,
    const float* __restrict__ f1,   const float* __restrict__ f2,
    const float* __restrict__ W1,   const float* __restrict__ b1,
    const float* __restrict__ W2,   const float* __restrict__ b2,
    const float* __restrict__ W3,   const float* __restrict__ b3,
    float* __restrict__ out)
{
  __shared__ __align__(16) char smem[SMEM_BYTES];
  __shared__ float wv[64][4];
  __shared__ int   iv[64][4];

  float4* cand = (float4*)smem;
  float*  mgK  = (float*)(smem + 16384);   // [3][64][5]
  int*    mgI  = (int*)(smem + 20224);     // [3][64][5]

  const int t = threadIdx.x;
  const int r = t & 63;              // lane = query row within block
  const int g = t >> 6;              // wave id 0..3
  const int qb = blockIdx.x * 64;
  const int batch = qb >> 14;        // 16384 queries per batch
  const float* xz2b = xyz2 + (size_t)batch * NPTS * 3;
  const float* f2b  = f2   + (size_t)batch * NPTS * C2;

  // ======================= Phase A: exact 3-NN =======================
  const int q = qb + r;
  const float qx = xyz1[q * 3], qy = xyz1[q * 3 + 1], qz = xyz1[q * 3 + 2];
  const float nx = -2.f * qx, ny = -2.f * qy, nz = -2.f * qz;

  float k0 = 1e30f, k1 = 1e30f, k2 = 1e30f, k3 = 1e30f, k4 = 1e30f;
  int   i0 = 0, i1 = 0, i2 = 0, i3 = 0, i4 = 0;
  for (int pass = 0; pass < 4; ++pass) {
    __syncthreads();
    #pragma unroll
    for (int i = 0; i < 4; ++i) {
      int ci = t + 256 * i;                    // 0..1023
      const float* p = xz2b + (size_t)(pass * 1024 + ci) * 3;
      float x = p[0], y = p[1], z = p[2];
      cand[ci] = make_float4(x, y, z, x * x + y * y + z * z);
    }
    __syncthreads();
    // wave g scans staged slots [g*256, g*256+256): broadcast LDS reads
    const int base = g * 256, abase = pass * 1024 + base;
    for (int m = 0; m < 256; ++m) {
      float4 c = cand[base + m];
      float key = fmaf(nx, c.x, fmaf(ny, c.y, fmaf(nz, c.z, c.w)));
      if (key < k4) {
        int idx = abase + m;
        bool l3 = key < k3, l2 = key < k2, l1 = key < k1, l0 = key < k0;
        k4 = l3 ? k3 : key;              i4 = l3 ? i3 : idx;
        k3 = l2 ? k2 : (l3 ? key : k3);  i3 = l2 ? i2 : (l3 ? idx : i3);
        k2 = l1 ? k1 : (l2 ? key : k2);  i2 = l1 ? i1 : (l2 ? idx : i2);
        k1 = l0 ? k0 : (l1 ? key : k1);  i1 = l0 ? i0 : (l1 ? idx : i1);
        k0 = l0 ? key : k0;              i0 = l0 ? idx : i0;
      }
    }
  }
  if (g > 0) {
    int base = ((g - 1) * 64 + r) * 5;
    mgK[base]     = k0; mgI[base]     = i0;
    mgK[base + 1] = k1; mgI[base + 1] = i1;
    mgK[base + 2] = k2; mgI[base + 2] = i2;
    mgK[base + 3] = k3; mgI[base + 3] = i3;
    mgK[base + 4] = k4; mgI[base + 4] = i4;
  }
  __syncthreads();

  if (g == 0) {
    // exact f64 rescore of the 20 survivors (f32 inputs -> f64 products are
    // exact; selection matches an exact reference; tie-break lower index)
    const double x1 = (double)qx, y1 = (double)qy, z1 = (double)qz;
    const double sq1 = x1 * x1 + y1 * y1 + z1 * z1;
    double d0 = 1e300, d1 = 1e300, d2 = 1e300;
    int j0 = 0, j1 = 0, j2 = 0;
    int surv[20];
    surv[0] = i0; surv[1] = i1; surv[2] = i2; surv[3] = i3; surv[4] = i4;
    #pragma unroll
    for (int w = 0; w < 3; ++w)
      #pragma unroll
      for (int s = 0; s < 5; ++s)
        surv[5 + w * 5 + s] = mgI[(w * 64 + r) * 5 + s];
    #pragma unroll
    for (int s = 0; s < 20; ++s) {
      int idx = surv[s] & (NPTS - 1);
      const float* p2 = xz2b + (size_t)idx * 3;
      double x2 = (double)p2[0], y2 = (double)p2[1], z2 = (double)p2[2];
      double d = sq1 + (x2 * x2 + y2 * y2 + z2 * z2)
                     - 2.0 * (x1 * x2 + y1 * y2 + z1 * z2);
      bool c2 = (d < d2) || (d == d2 && idx < j2);
      bool c1 = (d < d1) || (d == d1 && idx < j1);
      bool c0 = (d < d0) || (d == d0 && idx < j0);
      d2 = c1 ? d1 : (c2 ? d : d2);  j2 = c1 ? j1 : (c2 ? idx : j2);
      d1 = c0 ? d0 : (c1 ? d : d1);  j1 = c0 ? j0 : (c1 ? idx : j1);
      d0 = c0 ? d : d0;              j0 = c0 ? idx : j0;
    }
    float f0 = fmaxf((float)d0, 1e-10f);
    float f1v = fmaxf((float)d1, 1e-10f);
    float f2v = fmaxf((float)d2, 1e-10f);
    float r0 = 1.f / f0, r1 = 1.f / f1v, r2 = 1.f / f2v;
    float inv = 1.f / (r0 + r1 + r2);
    wv[r][0] = r0 * inv; wv[r][1] = r1 * inv; wv[r][2] = r2 * inv; wv[r][3] = 0.f;
    iv[r][0] = j0; iv[r][1] = j1; iv[r][2] = j2; iv[r][3] = 0;
  }

  // ======================= Phase B: MLP (f32 VALU) =======================
  float* Xs = (float*)smem;                // [64][129] f32, stride 129
  float* Hh = (float*)smem;                // [64][129] f32, stride 129

  // ---- Layer 1: accA = relu(X @ W1 + b1), X staged in 3 chunks of 128 ch
  float accA[64];
  #pragma unroll
  for (int j = 0; j < 64; ++j) accA[j] = 0.f;

  for (int c = 0; c < 3; ++c) {
    __syncthreads();                       // prior readers done (A or chunk c-1)
    #pragma unroll
    for (int i = 0; i < 32; ++i) {
      int e = t + 256 * i;                 // 0..8191
      int m = e >> 7, ch = e & 127;
      float val;
      if (c == 0) {
        val = f1[(size_t)(qb + m) * C1 + ch];
      } else {
        int cg = (c - 1) * 128 + ch;
        float w0 = wv[m][0], w1 = wv[m][1], w2 = wv[m][2];
        int a0 = iv[m][0] & (NPTS - 1);
        int a1 = iv[m][1] & (NPTS - 1);
        int a2 = iv[m][2] & (NPTS - 1);
        val = w0 * f2b[(size_t)a0 * C2 + cg]
            + w1 * f2b[(size_t)a1 * C2 + cg]
            + w2 * f2b[(size_t)a2 * C2 + cg];
      }
      Xs[m * 129 + ch] = val;
    }
    __syncthreads();
    for (int k = 0; k < 128; ++k) {
      float xv = Xs[r * 129 + k];          // stride 129: conflict-free
      const float* wp = W1 + (size_t)(c * 128 + k) * 256 + g * 64;
      #pragma unroll
      for (int j = 0; j < 64; ++j) accA[j] = fmaf(xv, wp[j], accA[j]);
    }
  }
  #pragma unroll
  for (int j = 0; j < 64; ++j)
    accA[j] = fmaxf(accA[j] + b1[g * 64 + j], 0.f);

  // ---- Layer 2: acc2 = relu(H1 @ W2 + b2), H1 via LDS in two halves
  float acc2[64];
  #pragma unroll
  for (int j = 0; j < 64; ++j) acc2[j] = 0.f;
  for (int h = 0; h < 2; ++h) {
    __syncthreads();
    if ((g >> 1) == h) {
      int cb = (g & 1) * 64;
      #pragma unroll
      for (int j = 0; j < 64; ++j) Hh[r * 129 + cb + j] = accA[j];
    }
    __syncthreads();
    for (int k = 0; k < 128; ++k) {
      float hv = Hh[r * 129 + k];
      const float* wp = W2 + (size_t)(h * 128 + k) * 256 + g * 64;
      #pragma unroll
      for (int j = 0; j < 64; ++j) acc2[j] = fmaf(hv, wp[j], acc2[j]);
    }
  }
  #pragma unroll
  for (int j = 0; j < 64; ++j)
    acc2[j] = fmaxf(acc2[j] + b2[g * 64 + j], 0.f);

  // ---- Layer 3: out = H2 @ W3 + b3
  float acc3[32];
  #pragma unroll
  for (int j = 0; j < 32; ++j) acc3[j] = 0.f;
  for (int h = 0; h < 2; ++h) {
    __syncthreads();
    if ((g >> 1) == h) {
      int cb = (g & 1) * 64;
      #pragma unroll
      for (int j = 0; j < 64; ++j) Hh[r * 129 + cb + j] = acc2[j];
    }
    __syncthreads();
    for (int k = 0; k < 128; ++k) {
      float hv = Hh[r * 129 + k];
      const float* wp = W3 + (size_t)(h * 128 + k) * 128 + g * 32;
      #pragma unroll
      for (int j = 0; j < 32; ++j) acc3[j] = fmaf(hv, wp[j], acc3[j]);
    }
  }
  #pragma unroll
  for (int j = 0; j < 32; ++j)
    out[(size_t)(qb + r) * COUT + g * 32 + j] = acc3[j] + b3[g * 32 + j];
}

// ---------------------------------------------------------------------------
extern "C" void kernel_launch(void* const* d_in, const int* in_sizes, int n_in,
                              void* d_out, int out_size, void* d_ws, size_t ws_size,
                              hipStream_t stream)
{
  (void)out_size; (void)d_ws; (void)ws_size;
  // Bind by element count (f32). ALL-OR-NOTHING: if any expected count is
  // missing, fall back to pure positional binding (protects against a
  // bytes-vs-elements or schema surprise cross-wiring tensors).
  static const int expect[10] = {196608, 49152, 8388608, 4194304,
                                 98304, 256, 65536, 256, 32768, 128};
  const void* p[10];
  bool ok = (n_in == 10);
  if (ok) {
    bool used[10] = {false};
    for (int e = 0; e < 10; ++e) {
      p[e] = nullptr;
      for (int i = 0; i < 10; ++i) {
        if (!used[i] && in_sizes[i] == expect[e]) {
          p[e] = d_in[i]; used[i] = true; break;
        }
      }
      if (!p[e]) { ok = false; break; }
    }
  }
  if (!ok)
    for (int e = 0; e < 10; ++e) p[e] = d_in[e < n_in ? e : (n_in - 1)];

  fused_fp<<<QT / 64, 256, 0, stream>>>(
      (const float*)p[0], (const float*)p[1],
      (const float*)p[2], (const float*)p[3],
      (const float*)p[4], (const float*)p[5],
      (const float*)p[6], (const float*)p[7],
      (const float*)p[8], (const float*)p[9],
      (float*)d_out);
}

// Round 7
// 691.656 us; speedup vs baseline: 3.8633x; 3.8633x over previous
//
#include <hip/hip_runtime.h>
#include <stdint.h>

// Problem constants (B=4, N=16384, NP=4096) — ALL TENSORS FLOAT32.
#define QT   65536
#define NPTS 4096
#define C1   128
#define C2   256
#define CIN  384
#define COUT 128

typedef _Float16 f16;
typedef __attribute__((ext_vector_type(8))) _Float16 f16x8;
typedef __attribute__((ext_vector_type(4))) float f32x4;

// LDS overlay (phases strictly barrier-separated):
//  Phase A: cand float4[1024] @0 (16384 B)
//           mgK f32[3*64*5] @16384 (3840 B); mgI i32[3*64*5] @20224 (3840 B)
//  Phase B: Hs f16[64][280] @0 (35840 B)  (H1, then overwritten with H2)
#define HS_STRIDE 280
#define SMEM_BYTES 35840

__global__ __launch_bounds__(256) void fused_fp(
    const float* __restrict__ xyz1, const float* __restrict__ xyz2,
    const float* __restrict__ f1,   const float* __restrict__ f2,
    const float* __restrict__ W1,   const float* __restrict__ b1,
    const float* __restrict__ W2,   const float* __restrict__ b2,
    const float* __restrict__ W3,   const float* __restrict__ b3,
    float* __restrict__ out)
{
  __shared__ __align__(16) char smem[SMEM_BYTES];
  __shared__ float wv[64][4];
  __shared__ int   iv[64][4];

  float4* cand = (float4*)smem;
  float*  mgK  = (float*)(smem + 16384);   // [3][64][5]
  int*    mgI  = (int*)(smem + 20224);     // [3][64][5]
  f16*    Hs   = (f16*)smem;               // [64][HS_STRIDE]

  const int t = threadIdx.x;
  const int r = t & 63;              // lane = query row within block
  const int g = t >> 6;              // wave id 0..3
  const int qb = blockIdx.x * 64;
  const int batch = qb >> 14;        // 16384 queries per batch
  const float* xz2b = xyz2 + (size_t)batch * NPTS * 3;
  const float* f2b  = f2   + (size_t)batch * NPTS * C2;

  // ======================= Phase A: exact 3-NN (R6-proven) ==================
  const int q = qb + r;
  const float qx = xyz1[q * 3], qy = xyz1[q * 3 + 1], qz = xyz1[q * 3 + 2];
  const float nx = -2.f * qx, ny = -2.f * qy, nz = -2.f * qz;

  float k0 = 1e30f, k1 = 1e30f, k2 = 1e30f, k3 = 1e30f, k4 = 1e30f;
  int   i0 = 0, i1 = 0, i2 = 0, i3 = 0, i4 = 0;
  for (int pass = 0; pass < 4; ++pass) {
    __syncthreads();
    #pragma unroll
    for (int i = 0; i < 4; ++i) {
      int ci = t + 256 * i;                    // 0..1023
      const float* p = xz2b + (size_t)(pass * 1024 + ci) * 3;
      float x = p[0], y = p[1], z = p[2];
      cand[ci] = make_float4(x, y, z, x * x + y * y + z * z);
    }
    __syncthreads();
    const int base = g * 256, abase = pass * 1024 + base;
    for (int m = 0; m < 256; ++m) {
      float4 c = cand[base + m];
      float key = fmaf(nx, c.x, fmaf(ny, c.y, fmaf(nz, c.z, c.w)));
      if (key < k4) {
        int idx = abase + m;
        bool l3 = key < k3, l2 = key < k2, l1 = key < k1, l0 = key < k0;
        k4 = l3 ? k3 : key;              i4 = l3 ? i3 : idx;
        k3 = l2 ? k2 : (l3 ? key : k3);  i3 = l2 ? i2 : (l3 ? idx : i3);
        k2 = l1 ? k1 : (l2 ? key : k2);  i2 = l1 ? i1 : (l2 ? idx : i2);
        k1 = l0 ? k0 : (l1 ? key : k1);  i1 = l0 ? i0 : (l1 ? idx : i1);
        k0 = l0 ? key : k0;              i0 = l0 ? idx : i0;
      }
    }
  }
  if (g > 0) {
    int base = ((g - 1) * 64 + r) * 5;
    mgK[base]     = k0; mgI[base]     = i0;
    mgK[base + 1] = k1; mgI[base + 1] = i1;
    mgK[base + 2] = k2; mgI[base + 2] = i2;
    mgK[base + 3] = k3; mgI[base + 3] = i3;
    mgK[base + 4] = k4; mgI[base + 4] = i4;
  }
  __syncthreads();

  if (g == 0) {
    const double x1 = (double)qx, y1 = (double)qy, z1 = (double)qz;
    const double sq1 = x1 * x1 + y1 * y1 + z1 * z1;
    double d0 = 1e300, d1 = 1e300, d2 = 1e300;
    int j0 = 0, j1 = 0, j2 = 0;
    int surv[20];
    surv[0] = i0; surv[1] = i1; surv[2] = i2; surv[3] = i3; surv[4] = i4;
    #pragma unroll
    for (int w = 0; w < 3; ++w)
      #pragma unroll
      for (int s = 0; s < 5; ++s)
        surv[5 + w * 5 + s] = mgI[(w * 64 + r) * 5 + s];
    #pragma unroll
    for (int s = 0; s < 20; ++s) {
      int idx = surv[s] & (NPTS - 1);
      const float* p2 = xz2b + (size_t)idx * 3;
      double x2 = (double)p2[0], y2 = (double)p2[1], z2 = (double)p2[2];
      double d = sq1 + (x2 * x2 + y2 * y2 + z2 * z2)
                     - 2.0 * (x1 * x2 + y1 * y2 + z1 * z2);
      bool c2 = (d < d2) || (d == d2 && idx < j2);
      bool c1 = (d < d1) || (d == d1 && idx < j1);
      bool c0 = (d < d0) || (d == d0 && idx < j0);
      d2 = c1 ? d1 : (c2 ? d : d2);  j2 = c1 ? j1 : (c2 ? idx : j2);
      d1 = c0 ? d0 : (c1 ? d : d1);  j1 = c0 ? j0 : (c1 ? idx : j1);
      d0 = c0 ? d : d0;              j0 = c0 ? idx : j0;
    }
    float e0 = fmaxf((float)d0, 1e-10f);
    float e1 = fmaxf((float)d1, 1e-10f);
    float e2 = fmaxf((float)d2, 1e-10f);
    float r0 = 1.f / e0, r1 = 1.f / e1, r2 = 1.f / e2;
    float inv = 1.f / (r0 + r1 + r2);
    wv[r][0] = r0 * inv; wv[r][1] = r1 * inv; wv[r][2] = r2 * inv; wv[r][3] = 0.f;
    iv[r][0] = j0; iv[r][1] = j1; iv[r][2] = j2; iv[r][3] = 0;
  }
  __syncthreads();   // wv/iv visible; Phase A smem (cand/mg*) dead

  // ======================= Phase B: MLP via f16 MFMA ========================
  // M=64 rows; wave g owns output cols [g*64, g*64+64) in L1/L2, [g*32,+32) L3.
  // A layout (16x16x32): row m = lane&15, k = quad*8 + j   (fragment = f16x8)
  // B layout:            col n = lane&15, k = quad*8 + j
  // C/D layout:          col = lane&15, row = quad*4 + reg
  const int l16 = r & 15, quad = r >> 4;
  const int nb = g * 64;

  // per-lane interp params for the 4 m-fragments (rows i*16+l16)
  float pw0[4], pw1[4], pw2[4]; int pa0[4], pa1[4], pa2[4];
  #pragma unroll
  for (int i = 0; i < 4; ++i) {
    int m = i * 16 + l16;
    pw0[i] = wv[m][0]; pw1[i] = wv[m][1]; pw2[i] = wv[m][2];
    pa0[i] = iv[m][0] & (NPTS - 1);
    pa1[i] = iv[m][1] & (NPTS - 1);
    pa2[i] = iv[m][2] & (NPTS - 1);
  }

  // ---- Layer 1: H1 = relu(X @ W1 + b1), K=384, N=256
  f32x4 acc[4][4];
  #pragma unroll
  for (int i = 0; i < 4; ++i)
    #pragma unroll
    for (int j = 0; j < 4; ++j) acc[i][j] = f32x4{0.f, 0.f, 0.f, 0.f};

  #pragma unroll
  for (int kc = 0; kc < CIN; kc += 32) {
    f16x8 a[4];
    if (kc < C1) {
      #pragma unroll
      for (int i = 0; i < 4; ++i) {
        const float* p = f1 + (size_t)(qb + i * 16 + l16) * C1 + kc + quad * 8;
        #pragma unroll
        for (int e = 0; e < 8; ++e) a[i][e] = (f16)p[e];
      }
    } else {
      const int cg = kc - C1 + quad * 8;
      #pragma unroll
      for (int i = 0; i < 4; ++i) {
        const float* p0 = f2b + (size_t)pa0[i] * C2 + cg;
        const float* p1 = f2b + (size_t)pa1[i] * C2 + cg;
        const float* p2 = f2b + (size_t)pa2[i] * C2 + cg;
        #pragma unroll
        for (int e = 0; e < 8; ++e) {
          float s = pw0[i] * p0[e] + pw1[i] * p1[e] + pw2[i] * p2[e];
          a[i][e] = (f16)s;
        }
      }
    }
    f16x8 b[4];
    #pragma unroll
    for (int j = 0; j < 4; ++j) {
      const float* wp = W1 + (size_t)(kc + quad * 8) * 256 + nb + j * 16 + l16;
      #pragma unroll
      for (int e = 0; e < 8; ++e) b[j][e] = (f16)wp[e * 256];
    }
    #pragma unroll
    for (int i = 0; i < 4; ++i)
      #pragma unroll
      for (int j = 0; j < 4; ++j)
        acc[i][j] = __builtin_amdgcn_mfma_f32_16x16x32_f16(a[i], b[j], acc[i][j], 0, 0, 0);
  }

  // epilogue -> Hs (safe: all waves passed Phase A barrier; no smem reads since)
  #pragma unroll
  for (int j = 0; j < 4; ++j) {
    float bv = b1[nb + j * 16 + l16];
    #pragma unroll
    for (int i = 0; i < 4; ++i)
      #pragma unroll
      for (int e = 0; e < 4; ++e) {
        int row = i * 16 + quad * 4 + e;
        Hs[row * HS_STRIDE + nb + j * 16 + l16] =
            (f16)fmaxf(acc[i][j][e] + bv, 0.f);
      }
  }
  __syncthreads();

  // ---- Layer 2: H2 = relu(H1 @ W2 + b2), K=256, N=256
  f32x4 acc2[4][4];
  #pragma unroll
  for (int i = 0; i < 4; ++i)
    #pragma unroll
    for (int j = 0; j < 4; ++j) acc2[i][j] = f32x4{0.f, 0.f, 0.f, 0.f};

  #pragma unroll
  for (int kc = 0; kc < 256; kc += 32) {
    f16x8 a[4];
    #pragma unroll
    for (int i = 0; i < 4; ++i)
      a[i] = *(const f16x8*)(Hs + (i * 16 + l16) * HS_STRIDE + kc + quad * 8);
    f16x8 b[4];
    #pragma unroll
    for (int j = 0; j < 4; ++j) {
      const float* wp = W2 + (size_t)(kc + quad * 8) * 256 + nb + j * 16 + l16;
      #pragma unroll
      for (int e = 0; e < 8; ++e) b[j][e] = (f16)wp[e * 256];
    }
    #pragma unroll
    for (int i = 0; i < 4; ++i)
      #pragma unroll
      for (int j = 0; j < 4; ++j)
        acc2[i][j] = __builtin_amdgcn_mfma_f32_16x16x32_f16(a[i], b[j], acc2[i][j], 0, 0, 0);
  }
  __syncthreads();                         // all H1 reads done before overwrite
  #pragma unroll
  for (int j = 0; j < 4; ++j) {
    float bv = b2[nb + j * 16 + l16];
    #pragma unroll
    for (int i = 0; i < 4; ++i)
      #pragma unroll
      for (int e = 0; e < 4; ++e) {
        int row = i * 16 + quad * 4 + e;
        Hs[row * HS_STRIDE + nb + j * 16 + l16] =
            (f16)fmaxf(acc2[i][j][e] + bv, 0.f);
      }
  }
  __syncthreads();

  // ---- Layer 3: OUT = H2 @ W3 + b3, K=256, N=128 (wave owns 32 cols)
  const int nb3 = g * 32;
  f32x4 acc3[4][2];
  #pragma unroll
  for (int i = 0; i < 4; ++i)
    #pragma unroll
    for (int j = 0; j < 2; ++j) acc3[i][j] = f32x4{0.f, 0.f, 0.f, 0.f};

  #pragma unroll
  for (int kc = 0; kc < 256; kc += 32) {
    f16x8 a[4];
    #pragma unroll
    for (int i = 0; i < 4; ++i)
      a[i] = *(const f16x8*)(Hs + (i * 16 + l16) * HS_STRIDE + kc + quad * 8);
    f16x8 b[2];
    #pragma unroll
    for (int j = 0; j < 2; ++j) {
      const float* wp = W3 + (size_t)(kc + quad * 8) * 128 + nb3 + j * 16 + l16;
      #pragma unroll
      for (int e = 0; e < 8; ++e) b[j][e] = (f16)wp[e * 128];
    }
    #pragma unroll
    for (int i = 0; i < 4; ++i)
      #pragma unroll
      for (int j = 0; j < 2; ++j)
        acc3[i][j] = __builtin_amdgcn_mfma_f32_16x16x32_f16(a[i], b[j], acc3[i][j], 0, 0, 0);
  }
  #pragma unroll
  for (int j = 0; j < 2; ++j) {
    int col = nb3 + j * 16 + l16;
    float bv = b3[col];
    #pragma unroll
    for (int i = 0; i < 4; ++i)
      #pragma unroll
      for (int e = 0; e < 4; ++e) {
        int row = i * 16 + quad * 4 + e;
        out[(size_t)(qb + row) * COUT + col] = acc3[i][j][e] + bv;
      }
  }
}

// ---------------------------------------------------------------------------
extern "C" void kernel_launch(void* const* d_in, const int* in_sizes, int n_in,
                              void* d_out, int out_size, void* d_ws, size_t ws_size,
                              hipStream_t stream)
{
  (void)out_size; (void)d_ws; (void)ws_size;
  static const int expect[10] = {196608, 49152, 8388608, 4194304,
                                 98304, 256, 65536, 256, 32768, 128};
  const void* p[10];
  bool ok = (n_in == 10);
  if (ok) {
    bool used[10] = {false};
    for (int e = 0; e < 10; ++e) {
      p[e] = nullptr;
      for (int i = 0; i < 10; ++i) {
        if (!used[i] && in_sizes[i] == expect[e]) {
          p[e] = d_in[i]; used[i] = true; break;
        }
      }
      if (!p[e]) { ok = false; break; }
    }
  }
  if (!ok)
    for (int e = 0; e < 10; ++e) p[e] = d_in[e < n_in ? e : (n_in - 1)];

  fused_fp<<<QT / 64, 256, 0, stream>>>(
      (const float*)p[0], (const float*)p[1],
      (const float*)p[2], (const float*)p[3],
      (const float*)p[4], (const float*)p[5],
      (const float*)p[6], (const float*)p[7],
      (const float*)p[8], (const float*)p[9],
      (float*)d_out);
}

// Round 8
// 610.554 us; speedup vs baseline: 4.3765x; 1.1328x over previous
//
#include <hip/hip_runtime.h>
#include <stdint.h>

// Problem constants (B=4, N=16384, NP=4096) — ALL TENSORS FLOAT32.
#define QT   65536
#define NPTS 4096
#define C1   128
#define C2   256
#define CIN  384
#define COUT 128

typedef _Float16 f16;
typedef __attribute__((ext_vector_type(8))) _Float16 f16x8;
typedef __attribute__((ext_vector_type(4))) float f32x4;

// LDS overlay (phases strictly barrier-separated):
//  Phase A: cand float4[1024]      @0      (16384)
//           mgK  f32[7][64][5]     @16384  (8960)
//           mgI  i32[7][64][5]     @25344  (8960)
//           wv   f32[64][4]        @34304  (1024)
//           iv   i32[64][4]        @35328  (1024)   end 36352
//  Phase B: Hs f16[64][280]        @0      (35840)  (H1, then H2)
#define HS_STRIDE 280
#define SMEM_BYTES 36352

__global__ __launch_bounds__(512) void fused_fp(
    const float* __restrict__ xyz1, const float* __restrict__ xyz2,
    const float* __restrict__ f1,   const float* __restrict__ f2,
    const float* __restrict__ W1,   const float* __restrict__ b1,
    const float* __restrict__ W2,   const float* __restrict__ b2,
    const float* __restrict__ W3,   const float* __restrict__ b3,
    float* __restrict__ out)
{
  __shared__ __align__(16) char smem[SMEM_BYTES];
  float4* cand = (float4*)smem;
  float*  mgK  = (float*)(smem + 16384);
  int*    mgI  = (int*)(smem + 25344);
  float*  wvp  = (float*)(smem + 34304);   // [64][4]
  int*    ivp  = (int*)(smem + 35328);     // [64][4]
  f16*    Hs   = (f16*)smem;               // [64][HS_STRIDE]

  const int t = threadIdx.x;
  const int r = t & 63;              // query row within block
  const int w = t >> 6;              // wave id 0..7
  const int qb = blockIdx.x * 64;
  const int batch = qb >> 14;        // 16384 queries per batch
  const float* xz2b = xyz2 + (size_t)batch * NPTS * 3;
  const float* f2b  = f2   + (size_t)batch * NPTS * C2;

  // ======================= Phase A: exact 3-NN =======================
  const int q = qb + r;
  const float qx = xyz1[q * 3], qy = xyz1[q * 3 + 1], qz = xyz1[q * 3 + 2];
  const float nx = -2.f * qx, ny = -2.f * qy, nz = -2.f * qz;

  float k0 = 1e30f, k1 = 1e30f, k2 = 1e30f, k3 = 1e30f, k4 = 1e30f;
  int   i0 = 0, i1 = 0, i2 = 0, i3 = 0, i4 = 0;

  auto ins = [&](float key, int idx) {
    bool l4 = key < k4, l3 = key < k3, l2 = key < k2, l1 = key < k1, l0 = key < k0;
    k4 = l3 ? k3 : (l4 ? key : k4);  i4 = l3 ? i3 : (l4 ? idx : i4);
    k3 = l2 ? k2 : (l3 ? key : k3);  i3 = l2 ? i2 : (l3 ? idx : i3);
    k2 = l1 ? k1 : (l2 ? key : k2);  i2 = l1 ? i1 : (l2 ? idx : i2);
    k1 = l0 ? k0 : (l1 ? key : k1);  i1 = l0 ? i0 : (l1 ? idx : i1);
    k0 = l0 ? key : k0;              i0 = l0 ? idx : i0;
  };

  for (int pass = 0; pass < 4; ++pass) {
    __syncthreads();
    #pragma unroll
    for (int i = 0; i < 2; ++i) {
      int ci = t + 512 * i;                    // 0..1023
      const float* p = xz2b + (size_t)(pass * 1024 + ci) * 3;
      float x = p[0], y = p[1], z = p[2];
      cand[ci] = make_float4(x, y, z, x * x + y * y + z * z);
    }
    __syncthreads();
    // wave w scans staged slots [w*128, w*128+128): broadcast LDS reads
    const float4* cc = cand + w * 128;
    const int abase = pass * 1024 + w * 128;
    for (int m = 0; m < 128; m += 4) {
      float4 c0 = cc[m], c1 = cc[m + 1], c2 = cc[m + 2], c3 = cc[m + 3];
      float e0 = fmaf(nx, c0.x, fmaf(ny, c0.y, fmaf(nz, c0.z, c0.w)));
      float e1 = fmaf(nx, c1.x, fmaf(ny, c1.y, fmaf(nz, c1.z, c1.w)));
      float e2 = fmaf(nx, c2.x, fmaf(ny, c2.y, fmaf(nz, c2.z, c2.w)));
      float e3 = fmaf(nx, c3.x, fmaf(ny, c3.y, fmaf(nz, c3.z, c3.w)));
      float mn = fminf(fminf(e0, e1), fminf(e2, e3));
      if (mn < k4) {                         // rare after warm-up
        ins(e0, abase + m);
        ins(e1, abase + m + 1);
        ins(e2, abase + m + 2);
        ins(e3, abase + m + 3);
      }
    }
  }
  if (w > 0) {
    int base = ((w - 1) * 64 + r) * 5;
    mgK[base]     = k0; mgI[base]     = i0;
    mgK[base + 1] = k1; mgI[base + 1] = i1;
    mgK[base + 2] = k2; mgI[base + 2] = i2;
    mgK[base + 3] = k3; mgI[base + 3] = i3;
    mgK[base + 4] = k4; mgI[base + 4] = i4;
  }
  __syncthreads();

  if (w == 0) {
    // exact f64 rescore of the 40 survivors (selection exact; tie: low index)
    const double x1 = (double)qx, y1 = (double)qy, z1 = (double)qz;
    const double sq1 = x1 * x1 + y1 * y1 + z1 * z1;
    double d0 = 1e300, d1 = 1e300, d2 = 1e300;
    int j0 = 0, j1 = 0, j2 = 0;
    int surv[40];
    surv[0] = i0; surv[1] = i1; surv[2] = i2; surv[3] = i3; surv[4] = i4;
    #pragma unroll
    for (int wi = 0; wi < 7; ++wi)
      #pragma unroll
      for (int s = 0; s < 5; ++s)
        surv[5 + wi * 5 + s] = mgI[(wi * 64 + r) * 5 + s];
    #pragma unroll
    for (int s = 0; s < 40; ++s) {
      int idx = surv[s] & (NPTS - 1);
      const float* p2 = xz2b + (size_t)idx * 3;
      double x2 = (double)p2[0], y2 = (double)p2[1], z2 = (double)p2[2];
      double d = sq1 + (x2 * x2 + y2 * y2 + z2 * z2)
                     - 2.0 * (x1 * x2 + y1 * y2 + z1 * z2);
      bool c2 = (d < d2) || (d == d2 && idx < j2);
      bool c1 = (d < d1) || (d == d1 && idx < j1);
      bool c0 = (d < d0) || (d == d0 && idx < j0);
      d2 = c1 ? d1 : (c2 ? d : d2);  j2 = c1 ? j1 : (c2 ? idx : j2);
      d1 = c0 ? d0 : (c1 ? d : d1);  j1 = c0 ? j0 : (c1 ? idx : j1);
      d0 = c0 ? d : d0;              j0 = c0 ? idx : j0;
    }
    float e0 = fmaxf((float)d0, 1e-10f);
    float e1 = fmaxf((float)d1, 1e-10f);
    float e2 = fmaxf((float)d2, 1e-10f);
    float r0 = 1.f / e0, r1 = 1.f / e1, r2 = 1.f / e2;
    float inv = 1.f / (r0 + r1 + r2);
    wvp[r * 4 + 0] = r0 * inv; wvp[r * 4 + 1] = r1 * inv;
    wvp[r * 4 + 2] = r2 * inv; wvp[r * 4 + 3] = 0.f;
    ivp[r * 4 + 0] = j0; ivp[r * 4 + 1] = j1; ivp[r * 4 + 2] = j2; ivp[r * 4 + 3] = 0;
  }
  __syncthreads();

  // ======================= Phase B: MLP via f16 MFMA ========================
  // M=64 rows; wave w owns output cols [w*32,+32) in L1/L2, [w*16,+16) in L3.
  const int l16 = r & 15, quad = r >> 4;
  const int nb = w * 32;

  // preload interp params for the 4 m-fragments (rows i*16+l16)
  float pw0[4], pw1[4], pw2[4]; int pa0[4], pa1[4], pa2[4];
  #pragma unroll
  for (int i = 0; i < 4; ++i) {
    int m = i * 16 + l16;
    pw0[i] = wvp[m * 4 + 0]; pw1[i] = wvp[m * 4 + 1]; pw2[i] = wvp[m * 4 + 2];
    pa0[i] = ivp[m * 4 + 0] & (NPTS - 1);
    pa1[i] = ivp[m * 4 + 1] & (NPTS - 1);
    pa2[i] = ivp[m * 4 + 2] & (NPTS - 1);
  }
  __syncthreads();   // wv/iv consumed; Hs region (full overlay) now free

  // ---- Layer 1: H1 = relu(X @ W1 + b1), K=384
  f32x4 acc[4][2];
  #pragma unroll
  for (int i = 0; i < 4; ++i)
    #pragma unroll
    for (int j = 0; j < 2; ++j) acc[i][j] = f32x4{0.f, 0.f, 0.f, 0.f};

  #pragma unroll
  for (int kc = 0; kc < CIN; kc += 32) {
    f16x8 a[4];
    if (kc < C1) {
      #pragma unroll
      for (int i = 0; i < 4; ++i) {
        const float* p = f1 + (size_t)(qb + i * 16 + l16) * C1 + kc + quad * 8;
        #pragma unroll
        for (int e = 0; e < 8; ++e) a[i][e] = (f16)p[e];
      }
    } else {
      const int cg = kc - C1 + quad * 8;
      #pragma unroll
      for (int i = 0; i < 4; ++i) {
        const float* p0 = f2b + (size_t)pa0[i] * C2 + cg;
        const float* p1 = f2b + (size_t)pa1[i] * C2 + cg;
        const float* p2 = f2b + (size_t)pa2[i] * C2 + cg;
        #pragma unroll
        for (int e = 0; e < 8; ++e)
          a[i][e] = (f16)(pw0[i] * p0[e] + pw1[i] * p1[e] + pw2[i] * p2[e]);
      }
    }
    f16x8 b[2];
    #pragma unroll
    for (int j = 0; j < 2; ++j) {
      const float* wp = W1 + (size_t)(kc + quad * 8) * 256 + nb + j * 16 + l16;
      #pragma unroll
      for (int e = 0; e < 8; ++e) b[j][e] = (f16)wp[e * 256];
    }
    #pragma unroll
    for (int i = 0; i < 4; ++i)
      #pragma unroll
      for (int j = 0; j < 2; ++j)
        acc[i][j] = __builtin_amdgcn_mfma_f32_16x16x32_f16(a[i], b[j], acc[i][j], 0, 0, 0);
  }
  #pragma unroll
  for (int j = 0; j < 2; ++j) {
    float bv = b1[nb + j * 16 + l16];
    #pragma unroll
    for (int i = 0; i < 4; ++i)
      #pragma unroll
      for (int e = 0; e < 4; ++e) {
        int row = i * 16 + quad * 4 + e;
        Hs[row * HS_STRIDE + nb + j * 16 + l16] =
            (f16)fmaxf(acc[i][j][e] + bv, 0.f);
      }
  }
  __syncthreads();

  // ---- Layer 2: H2 = relu(H1 @ W2 + b2), K=256
  f32x4 acc2[4][2];
  #pragma unroll
  for (int i = 0; i < 4; ++i)
    #pragma unroll
    for (int j = 0; j < 2; ++j) acc2[i][j] = f32x4{0.f, 0.f, 0.f, 0.f};

  #pragma unroll
  for (int kc = 0; kc < 256; kc += 32) {
    f16x8 a[4];
    #pragma unroll
    for (int i = 0; i < 4; ++i)
      a[i] = *(const f16x8*)(Hs + (i * 16 + l16) * HS_STRIDE + kc + quad * 8);
    f16x8 b[2];
    #pragma unroll
    for (int j = 0; j < 2; ++j) {
      const float* wp = W2 + (size_t)(kc + quad * 8) * 256 + nb + j * 16 + l16;
      #pragma unroll
      for (int e = 0; e < 8; ++e) b[j][e] = (f16)wp[e * 256];
    }
    #pragma unroll
    for (int i = 0; i < 4; ++i)
      #pragma unroll
      for (int j = 0; j < 2; ++j)
        acc2[i][j] = __builtin_amdgcn_mfma_f32_16x16x32_f16(a[i], b[j], acc2[i][j], 0, 0, 0);
  }
  __syncthreads();                         // all H1 reads done before overwrite
  #pragma unroll
  for (int j = 0; j < 2; ++j) {
    float bv = b2[nb + j * 16 + l16];
    #pragma unroll
    for (int i = 0; i < 4; ++i)
      #pragma unroll
      for (int e = 0; e < 4; ++e) {
        int row = i * 16 + quad * 4 + e;
        Hs[row * HS_STRIDE + nb + j * 16 + l16] =
            (f16)fmaxf(acc2[i][j][e] + bv, 0.f);
      }
  }
  __syncthreads();

  // ---- Layer 3: OUT = H2 @ W3 + b3, K=256 (wave owns 16 cols)
  const int nb3 = w * 16;
  f32x4 acc3[4];
  #pragma unroll
  for (int i = 0; i < 4; ++i) acc3[i] = f32x4{0.f, 0.f, 0.f, 0.f};

  #pragma unroll
  for (int kc = 0; kc < 256; kc += 32) {
    f16x8 a[4];
    #pragma unroll
    for (int i = 0; i < 4; ++i)
      a[i] = *(const f16x8*)(Hs + (i * 16 + l16) * HS_STRIDE + kc + quad * 8);
    f16x8 b;
    {
      const float* wp = W3 + (size_t)(kc + quad * 8) * 128 + nb3 + l16;
      #pragma unroll
      for (int e = 0; e < 8; ++e) b[e] = (f16)wp[e * 128];
    }
    #pragma unroll
    for (int i = 0; i < 4; ++i)
      acc3[i] = __builtin_amdgcn_mfma_f32_16x16x32_f16(a[i], b, acc3[i], 0, 0, 0);
  }
  {
    int col = nb3 + l16;
    float bv = b3[col];
    #pragma unroll
    for (int i = 0; i < 4; ++i)
      #pragma unroll
      for (int e = 0; e < 4; ++e) {
        int row = i * 16 + quad * 4 + e;
        out[(size_t)(qb + row) * COUT + col] = acc3[i][e] + bv;
      }
  }
}

// ---------------------------------------------------------------------------
extern "C" void kernel_launch(void* const* d_in, const int* in_sizes, int n_in,
                              void* d_out, int out_size, void* d_ws, size_t ws_size,
                              hipStream_t stream)
{
  (void)out_size; (void)d_ws; (void)ws_size;
  static const int expect[10] = {196608, 49152, 8388608, 4194304,
                                 98304, 256, 65536, 256, 32768, 128};
  const void* p[10];
  bool ok = (n_in == 10);
  if (ok) {
    bool used[10] = {false};
    for (int e = 0; e < 10; ++e) {
      p[e] = nullptr;
      for (int i = 0; i < 10; ++i) {
        if (!used[i] && in_sizes[i] == expect[e]) {
          p[e] = d_in[i]; used[i] = true; break;
        }
      }
      if (!p[e]) { ok = false; break; }
    }
  }
  if (!ok)
    for (int e = 0; e < 10; ++e) p[e] = d_in[e < n_in ? e : (n_in - 1)];

  fused_fp<<<QT / 64, 512, 0, stream>>>(
      (const float*)p[0], (const float*)p[1],
      (const float*)p[2], (const float*)p[3],
      (const float*)p[4], (const float*)p[5],
      (const float*)p[6], (const float*)p[7],
      (const float*)p[8], (const float*)p[9],
      (float*)d_out);
}